// Round 10
// baseline (91.942 us; speedup 1.0000x reference)
//
#include <hip/hip_runtime.h>
#include <math.h>

// Problem constants
#define NB    64
#define L0    128
#define C0    16
#define KW    5
#define NF    8
#define CH1   128
#define CH2   1024
#define CH3   8192
#define NCHUNK 8
#define NS     4
#define SLICE  29
#define TROWS  (SLICE + 4)    // 33
#define Y1R    (SLICE + 8)    // 37
#define STR    (SLICE + 12)   // 41
#define NFH    4
#define NBATCH 4              // batches per block (2 blocks/CU)
#define NBG    (NB / NBATCH)  // 16

typedef float v4f __attribute__((ext_vector_type(4)));

__device__ __forceinline__ v4f splat(float s) { return (v4f){s, s, s, s}; }
// a*s + c elementwise -> v_pk_fma_f32 pairs on gfx950
__device__ __forceinline__ v4f vfma(v4f a, float s, v4f c) {
    return __builtin_elementwise_fma(a, splat(s), c);
}
__device__ __forceinline__ v4f vrelu(v4f a) {
    return __builtin_elementwise_max(a, splat(0.f));
}

// ---------------------------------------------------------------------------
// Fused conv1+conv2+conv3+dense. NBATCH=4 packed-fp32; R10: main loop FULLY
// unrolled (window movs/addressing vanish, tile reads CSE to 33 ds_read_b128,
// compiler software-pipelines the 58 W loads at register-budget depth), and
// k3/b3 weights + first W pair are issued BEFORE the conv1/conv2 preamble so
// their cold-miss latency overlaps staging compute instead of serializing
// after the last barrier. Grid (8,16,4)=512 blocks, 2 blocks/CU (78.5 KB LDS),
// launch_bounds(256,2) -> 256-VGPR budget (est. ~120 live, no spills).
// blockIdx.x = chunk pins each 950 KB W-slice to one XCD's L2 (linear%8).
// ---------------------------------------------------------------------------
__global__ __launch_bounds__(256, 2) void actor_fused_kernel(
    const float* __restrict__ state,   // [64][128][16]
    const float* __restrict__ k1,      // [5][1][128]
    const float* __restrict__ b1,      // [128]
    const float* __restrict__ k2,      // [5][1][1024]
    const float* __restrict__ b2,      // [1024]
    const float* __restrict__ k3,      // [5][1][8192]
    const float* __restrict__ b3,      // [8192]
    const float* __restrict__ W,       // [950272][2]
    float* __restrict__ partials)      // [64][8][4][2]
{
    const int chunk = blockIdx.x;      // 0..7
    const int bg    = blockIdx.y;      // 0..15
    const int slice = blockIdx.z;      // 0..3
    const int t0    = slice * SLICE;
    const int tid   = threadIdx.x;     // 0..255
    const int c3loc = tid >> 1;        // 0..127
    const int fh    = tid & 1;         // 0..1
    const int c3    = chunk * 128 + c3loc;

    __shared__ float s_state[NBATCH][STR][2];   // 1.3 KB
    __shared__ v4f   s_y1[Y1R][16];             // lanes = batches, 9.25 KB
    __shared__ v4f   tile[TROWS][128];          // lanes = batches, 66 KB

    // ---- EARLY global loads: issued before any LDS dependency, their
    // latency overlaps the whole conv1/conv2 preamble ----
    const v4f* __restrict__ wb =
        (const v4f*)W + (size_t)t0 * 4096 + (size_t)c3 * 4 + fh * 2;
    v4f p0 = wb[0];                    // W[t=0] pair, used in unrolled iter 0
    v4f p1 = wb[1];

    float kw[KW][NFH], bv[NFH];
#pragma unroll
    for (int k = 0; k < KW; ++k)
#pragma unroll
        for (int f = 0; f < NFH; ++f)
            kw[k][f] = k3[k * CH3 + c3 * NF + fh * NFH + f];
#pragma unroll
    for (int f = 0; f < NFH; ++f)
        bv[f] = b3[c3 * NF + fh * NFH + f];

    // ---- stage state: wave bb = tid>>6 owns batch bg*4+bb ----
    {
        int bb = tid >> 6, lt = tid & 63;
        const float* sp = state + (size_t)(bg * NBATCH + bb) * L0 * C0
                        + (size_t)t0 * C0 + chunk * 2;
        for (int i = lt; i < STR * 2; i += 64) {
            int r = i >> 1, c = i & 1;
            s_state[bb][r][c] = sp[r * C0 + c];
        }
    }
    __syncthreads();

    // ---- conv1: wave bb writes component bb of s_y1 ----
    {
        int bb = tid >> 6, lt = tid & 63;
        for (int i = lt; i < Y1R * 16; i += 64) {
            int r = i >> 4, jloc = i & 15;
            int j = chunk * 16 + jloc;
            int cloc = jloc >> 3;
            float acc = b1[j];
#pragma unroll
            for (int k = 0; k < KW; ++k)
                acc = fmaf(s_state[bb][r + k][cloc], k1[k * CH1 + j], acc);
            ((float*)&s_y1[r][jloc])[bb] = fmaxf(acc, 0.f);
        }
    }
    __syncthreads();

    // ---- conv2: col c = tid&127, row-half h = tid>>7, 4 batches packed ----
    {
        int c = tid & 127, h = tid >> 7;
        int m = chunk * 128 + c;
        int jloc = c >> 3;
        float kk[KW], b2v = b2[m];
#pragma unroll
        for (int k = 0; k < KW; ++k) kk[k] = k2[k * CH2 + m];
        int r0i = h ? 17 : 0, r1i = h ? TROWS : 17;
        v4f u0 = s_y1[r0i + 0][jloc];
        v4f u1 = s_y1[r0i + 1][jloc];
        v4f u2 = s_y1[r0i + 2][jloc];
        v4f u3 = s_y1[r0i + 3][jloc];
        for (int r = r0i; r < r1i; ++r) {
            v4f u4 = s_y1[r + 4][jloc];
            v4f acc = splat(b2v);
            acc = vfma(u0, kk[0], acc);
            acc = vfma(u1, kk[1], acc);
            acc = vfma(u2, kk[2], acc);
            acc = vfma(u3, kk[3], acc);
            acc = vfma(u4, kk[4], acc);
            tile[r][c] = vrelu(acc);
            u0 = u1; u1 = u2; u2 = u3; u3 = u4;
        }
    }

    __syncthreads();   // tile ready

    // ---- main loop: FULLY UNROLLED conv3 + relu + dense ----
    v4f accx = splat(0.f), accy = splat(0.f);

#pragma unroll
    for (int t = 0; t < SLICE; ++t) {
        v4f q0, q1;
        if (t == 0) { q0 = p0; q1 = p1; }
        else {
            q0 = wb[(size_t)t * 4096];
            q1 = wb[(size_t)t * 4096 + 1];
        }
        // 5-row window; overlapping reads CSE across unrolled iterations
        v4f a0 = tile[t + 0][c3loc];
        v4f a1 = tile[t + 1][c3loc];
        v4f a2 = tile[t + 2][c3loc];
        v4f a3 = tile[t + 3][c3loc];
        v4f a4 = tile[t + 4][c3loc];

        v4f v0 = splat(bv[0]), v1 = splat(bv[1]);
        v4f v2 = splat(bv[2]), v3 = splat(bv[3]);
        v0 = vfma(a0, kw[0][0], v0); v1 = vfma(a0, kw[0][1], v1);
        v2 = vfma(a0, kw[0][2], v2); v3 = vfma(a0, kw[0][3], v3);
        v0 = vfma(a1, kw[1][0], v0); v1 = vfma(a1, kw[1][1], v1);
        v2 = vfma(a1, kw[1][2], v2); v3 = vfma(a1, kw[1][3], v3);
        v0 = vfma(a2, kw[2][0], v0); v1 = vfma(a2, kw[2][1], v1);
        v2 = vfma(a2, kw[2][2], v2); v3 = vfma(a2, kw[2][3], v3);
        v0 = vfma(a3, kw[3][0], v0); v1 = vfma(a3, kw[3][1], v1);
        v2 = vfma(a3, kw[3][2], v2); v3 = vfma(a3, kw[3][3], v3);
        v0 = vfma(a4, kw[4][0], v0); v1 = vfma(a4, kw[4][1], v1);
        v2 = vfma(a4, kw[4][2], v2); v3 = vfma(a4, kw[4][3], v3);
        v0 = vrelu(v0); v1 = vrelu(v1); v2 = vrelu(v2); v3 = vrelu(v3);

        accx = vfma(v0, q0.x, accx); accy = vfma(v0, q0.y, accy);
        accx = vfma(v1, q0.z, accx); accy = vfma(v1, q0.w, accy);
        accx = vfma(v2, q1.x, accx); accy = vfma(v2, q1.y, accy);
        accx = vfma(v3, q1.z, accx); accy = vfma(v3, q1.w, accy);
    }

    // ---- reductions: 4 batches x 2 outputs ----
    float ax[NBATCH] = {accx.x, accx.y, accx.z, accx.w};
    float ay[NBATCH] = {accy.x, accy.y, accy.z, accy.w};
#pragma unroll
    for (int bb = 0; bb < NBATCH; ++bb)
#pragma unroll
        for (int d = 32; d >= 1; d >>= 1) {
            ax[bb] += __shfl_down(ax[bb], d, 64);
            ay[bb] += __shfl_down(ay[bb], d, 64);
        }
    __shared__ float red[4][NBATCH][2];
    int wave = tid >> 6, lane = tid & 63;
    if (lane == 0) {
#pragma unroll
        for (int bb = 0; bb < NBATCH; ++bb) {
            red[wave][bb][0] = ax[bb];
            red[wave][bb][1] = ay[bb];
        }
    }
    __syncthreads();
    if (tid < NBATCH * 2) {
        int bb = tid >> 1, a = tid & 1;
        float s = (red[0][bb][a] + red[1][bb][a]) + (red[2][bb][a] + red[3][bb][a]);
        int b = bg * NBATCH + bb;
        partials[(((size_t)b * NCHUNK + chunk) * NS + slice) * 2 + a] = s;
    }
}

// ---------------------------------------------------------------------------
__global__ __launch_bounds__(128) void finish_kernel(
    const float* __restrict__ partials,  // [64][8][4][2]
    const float* __restrict__ bd,        // [2]
    float* __restrict__ out)             // [64][2]
{
    int i = threadIdx.x;
    int b = i >> 1, a = i & 1;
    float s = bd[a];
#pragma unroll
    for (int p = 0; p < NCHUNK * NS; ++p)
        s += partials[((size_t)b * NCHUNK * NS + p) * 2 + a];
    out[b * 2 + a] = tanhf(s);
}

extern "C" void kernel_launch(void* const* d_in, const int* in_sizes, int n_in,
                              void* d_out, int out_size, void* d_ws, size_t ws_size,
                              hipStream_t stream) {
    const float* state = (const float*)d_in[0];
    const float* k1    = (const float*)d_in[1];
    const float* b1    = (const float*)d_in[2];
    const float* k2    = (const float*)d_in[3];
    const float* b2    = (const float*)d_in[4];
    const float* k3    = (const float*)d_in[5];
    const float* b3    = (const float*)d_in[6];
    const float* W     = (const float*)d_in[7];
    const float* bd    = (const float*)d_in[8];
    float* out = (float*)d_out;

    float* partials = (float*)d_ws;   // 64*8*4*2 fp32 = 16 KB

    dim3 grid(NCHUNK, NBG, NS);
    actor_fused_kernel<<<grid, 256, 0, stream>>>(
        state, k1, b1, k2, b2, k3, b3, W, partials);

    finish_kernel<<<1, 128, 0, stream>>>(partials, bd, out);
}